// Round 12
// baseline (435.575 us; speedup 1.0000x reference)
//
#include <hip/hip_runtime.h>
#include <math.h>

// GCN 2-layer, N=100000, E=3200000, feats 2->16->2.
// R12: cross-round model: every LDS-atomic-per-edge costs ~23us device-wide
// (~120cy serialized RMW per wave-op). R7/R8/R10 all spent ~9 atomics/edge ->
// all ~203-239us. This round: partition keeps 4 atomics/edge (pass1+pass2),
// but degree + BOTH aggregations become atomic-free "broadcast-scalar" wave
// scans: lane owns dst node (bucket=64 nodes), wave walks the bucket edge
// list with WAVE-UNIFORM loads (1 transaction/edge, broadcast; no divergent
// gathers, no LDS atomics), predicated register accumulation.

constexpr int N = 100000;
constexpr int CLOG = 11;
constexpr int CN = 1 << CLOG;                 // 2048 nodes per coarse range
constexpr int NC = 49;                        // coarse ranges (dst>>11)
constexpr int KF = NC * 32;                   // fine buckets (64 nodes each)
constexpr int K = (N + 63) / 64;              // 1563 buckets with real nodes
constexpr int CAP1 = 68608;                   // coarse cap (mean 65306 + ~13s)
constexpr int CAPF = 2560;                    // fine cap (mean 2048 + ~11s)
constexpr int BSP = 512;
constexpr int ECHUNK = 8192;
constexpr int EPT = ECHUNK / BSP;             // 16
constexpr int MAXCH = 9;                      // chunks per coarse region
constexpr int WCH = CAPF / 4;                 // 640 entries per wave in agg

__global__ __launch_bounds__(BSP) void k_pass1(const int* __restrict__ src,
                                               const int* __restrict__ dst, int E,
                                               int* __restrict__ gfill1,
                                               int* __restrict__ slotsC) {
    __shared__ int hist[NC];
    __shared__ int base[NC];
    int t = threadIdx.x;
    if (t < NC) hist[t] = 0;
    __syncthreads();
    int s[EPT], d[EPT];
    int ebase = blockIdx.x * ECHUNK + t * EPT;
#pragma unroll
    for (int k = 0; k < EPT / 4; k++) {
        int idx = ebase + 4 * k;
        if (idx + 3 < E) {
            *(int4*)(s + 4 * k) = *(const int4*)(src + idx);
            *(int4*)(d + 4 * k) = *(const int4*)(dst + idx);
        } else {
            for (int j = 0; j < 4; j++) {
                s[4 * k + j] = (idx + j < E) ? src[idx + j] : -1;
                d[4 * k + j] = (idx + j < E) ? dst[idx + j] : -1;
            }
        }
    }
#pragma unroll
    for (int k = 0; k < EPT; k++)
        if (d[k] >= 0) atomicAdd(&hist[d[k] >> CLOG], 1);
    __syncthreads();
    if (t < NC) {
        int c = hist[t];
        base[t] = c ? atomicAdd(&gfill1[t], c) : 0;
        hist[t] = 0;  // cursor
    }
    __syncthreads();
#pragma unroll
    for (int k = 0; k < EPT; k++) {
        if (d[k] >= 0) {
            int bin = d[k] >> CLOG;
            int r = atomicAdd(&hist[bin], 1);  // LDS
            int pos = base[bin] + r;
            if (pos < CAP1) slotsC[bin * CAP1 + pos] = (s[k] << CLOG) | (d[k] & (CN - 1));
        }
    }
}

// pass2: split coarse bucket by dstloc high-5 bits -> fine 64-node buckets.
// Fine bucket id == (dst >> 6). Payload = (src<<6)|dstloc6.
__global__ __launch_bounds__(BSP) void k_pass2(const int* __restrict__ gfill1,
                                               const int* __restrict__ slotsC,
                                               int* __restrict__ gfillF,
                                               int* __restrict__ slotsF) {
    __shared__ int hist[32];
    __shared__ int base[32];
    int c = blockIdx.x / MAXCH;
    int j = blockIdx.x % MAXCH;
    int t = threadIdx.x;
    if (t < 32) hist[t] = 0;
    __syncthreads();
    int fill = min(gfill1[c], CAP1);
    int e0 = j * ECHUNK;
    int e1 = min(fill, e0 + ECHUNK);
    const int* row = slotsC + c * CAP1;
    int v[EPT];
    int ebase = e0 + t * EPT;
#pragma unroll
    for (int k = 0; k < EPT / 4; k++) {
        int idx = ebase + 4 * k;
        if (idx + 3 < e1) {
            *(int4*)(v + 4 * k) = *(const int4*)(row + idx);
        } else {
            for (int jj = 0; jj < 4; jj++) v[4 * k + jj] = (idx + jj < e1) ? row[idx + jj] : -1;
        }
    }
#pragma unroll
    for (int k = 0; k < EPT; k++)
        if (v[k] >= 0) atomicAdd(&hist[(v[k] >> 6) & 31], 1);
    __syncthreads();
    if (t < 32) {
        int cc = hist[t];
        base[t] = cc ? atomicAdd(&gfillF[c * 32 + t], cc) : 0;
        hist[t] = 0;
    }
    __syncthreads();
#pragma unroll
    for (int k = 0; k < EPT; k++) {
        if (v[k] >= 0) {
            int fb = (v[k] >> 6) & 31;
            int r = atomicAdd(&hist[fb], 1);  // LDS
            int pos = base[fb] + r;
            if (pos < CAPF)
                slotsF[(size_t)(c * 32 + fb) * CAPF + pos] = ((v[k] >> CLOG) << 6) | (v[k] & 63);
        }
    }
}

// degree via broadcast wave scan (zero atomics) + fused dinv/sx epilogue.
__global__ __launch_bounds__(256) void k_deg(const int* __restrict__ gfillF,
                                             const int* __restrict__ slotsF,
                                             const float* __restrict__ x,
                                             float* __restrict__ dinv,
                                             float2* __restrict__ sx) {
    __shared__ int pdeg[4][64];
    int b = blockIdx.x, t = threadIdx.x, w = t >> 6, lane = t & 63;
    int count = min(gfillF[b], CAPF);
    const int* row = slotsF + (size_t)b * CAPF;
    int j0 = w * WCH, j1 = min(count, j0 + WCH);
    int deg = 0;
    int j = j0;
    for (; j + 8 <= j1; j += 8) {
        int e[8];
#pragma unroll
        for (int k = 0; k < 8; k++) e[k] = row[j + k];
#pragma unroll
        for (int k = 0; k < 8; k++) deg += ((e[k] & 63) == lane) ? 1 : 0;
    }
    for (; j < j1; j++) deg += ((row[j] & 63) == lane) ? 1 : 0;
    pdeg[w][lane] = deg;
    __syncthreads();
    if (t < 64) {
        int node = b * 64 + t;
        if (node < N) {
            int d = pdeg[0][t] + pdeg[1][t] + pdeg[2][t] + pdeg[3][t];
            float di = rsqrtf((float)(d + 1));
            dinv[node] = di;
            float2 xv = ((const float2*)x)[node];
            sx[node] = make_float2(xv.x * di, xv.y * di);
        }
    }
}

// layer1 aggregate via broadcast wave scan + fused MLP -> sz.
__global__ __launch_bounds__(256) void k_agg1(const int* __restrict__ gfillF,
                                              const int* __restrict__ slotsF,
                                              const float* __restrict__ dinv,
                                              const float2* __restrict__ sx,
                                              const float* __restrict__ W1,
                                              const float* __restrict__ b1,
                                              const float* __restrict__ W2,
                                              float2* __restrict__ sz) {
    __shared__ float pax[4][64], pay[4][64];
    __shared__ float sW1[32], sb1[16], sW2[32];
    int t = threadIdx.x;
    if (t < 32) sW1[t] = W1[t];
    if (t >= 32 && t < 48) sb1[t - 32] = b1[t - 32];
    if (t >= 48 && t < 80) sW2[t - 48] = W2[t - 48];
    int b = blockIdx.x, w = t >> 6, lane = t & 63;
    int count = min(gfillF[b], CAPF);
    const int* row = slotsF + (size_t)b * CAPF;
    int j0 = w * WCH, j1 = min(count, j0 + WCH);
    float a0 = 0.f, a1 = 0.f;
    int j = j0;
    for (; j + 8 <= j1; j += 8) {
        int e[8];
#pragma unroll
        for (int k = 0; k < 8; k++) e[k] = row[j + k];
        float2 v[8];
#pragma unroll
        for (int k = 0; k < 8; k++) v[k] = sx[e[k] >> 6];  // wave-uniform address
#pragma unroll
        for (int k = 0; k < 8; k++) {
            bool m = (e[k] & 63) == lane;
            a0 += m ? v[k].x : 0.f;
            a1 += m ? v[k].y : 0.f;
        }
    }
    for (; j < j1; j++) {
        int e = row[j];
        float2 v = sx[e >> 6];
        bool m = (e & 63) == lane;
        a0 += m ? v.x : 0.f;
        a1 += m ? v.y : 0.f;
    }
    pax[w][lane] = a0;
    pay[w][lane] = a1;
    __syncthreads();
    if (t < 64) {
        int node = b * 64 + t;
        if (node < N) {
            float di = dinv[node];
            float2 sv = sx[node];
            float A0 = (pax[0][t] + pax[1][t] + pax[2][t] + pax[3][t] + sv.x) * di;
            float A1 = (pay[0][t] + pay[1][t] + pay[2][t] + pay[3][t] + sv.y) * di;
            float z0 = 0.f, z1 = 0.f;
#pragma unroll
            for (int k = 0; k < 16; k++) {
                float h = fmaf(A0, sW1[k], fmaf(A1, sW1[16 + k], sb1[k]));
                h = fmaxf(h, 0.f);
                z0 = fmaf(h, sW2[2 * k + 0], z0);
                z1 = fmaf(h, sW2[2 * k + 1], z1);
            }
            sz[node] = make_float2(z0 * di, z1 * di);
        }
    }
}

// layer2 aggregate via broadcast wave scan + bias + log_softmax -> out.
__global__ __launch_bounds__(256) void k_agg2(const int* __restrict__ gfillF,
                                              const int* __restrict__ slotsF,
                                              const float* __restrict__ dinv,
                                              const float2* __restrict__ sz,
                                              const float* __restrict__ b2,
                                              float2* __restrict__ out) {
    __shared__ float pax[4][64], pay[4][64];
    int b = blockIdx.x, t = threadIdx.x, w = t >> 6, lane = t & 63;
    int count = min(gfillF[b], CAPF);
    const int* row = slotsF + (size_t)b * CAPF;
    int j0 = w * WCH, j1 = min(count, j0 + WCH);
    float a0 = 0.f, a1 = 0.f;
    int j = j0;
    for (; j + 8 <= j1; j += 8) {
        int e[8];
#pragma unroll
        for (int k = 0; k < 8; k++) e[k] = row[j + k];
        float2 v[8];
#pragma unroll
        for (int k = 0; k < 8; k++) v[k] = sz[e[k] >> 6];
#pragma unroll
        for (int k = 0; k < 8; k++) {
            bool m = (e[k] & 63) == lane;
            a0 += m ? v[k].x : 0.f;
            a1 += m ? v[k].y : 0.f;
        }
    }
    for (; j < j1; j++) {
        int e = row[j];
        float2 v = sz[e >> 6];
        bool m = (e & 63) == lane;
        a0 += m ? v.x : 0.f;
        a1 += m ? v.y : 0.f;
    }
    pax[w][lane] = a0;
    pay[w][lane] = a1;
    __syncthreads();
    if (t < 64) {
        int node = b * 64 + t;
        if (node < N) {
            float di = dinv[node];
            float2 sv = sz[node];
            float v0 = fmaf(pax[0][t] + pax[1][t] + pax[2][t] + pax[3][t] + sv.x, di, b2[0]);
            float v1 = fmaf(pay[0][t] + pay[1][t] + pay[2][t] + pay[3][t] + sv.y, di, b2[1]);
            float m = fmaxf(v0, v1);
            float lse = m + logf(expf(v0 - m) + expf(v1 - m));
            out[node] = make_float2(v0 - lse, v1 - lse);
        }
    }
}

extern "C" void kernel_launch(void* const* d_in, const int* in_sizes, int n_in,
                              void* d_out, int out_size, void* d_ws, size_t ws_size,
                              hipStream_t stream) {
    const float* x  = (const float*)d_in[0];
    const int*   ei = (const int*)d_in[1];
    const float* W1 = (const float*)d_in[2];
    const float* b1 = (const float*)d_in[3];
    const float* W2 = (const float*)d_in[4];
    const float* b2 = (const float*)d_in[5];

    const int E = in_sizes[1] / 2;
    const int* src = ei;
    const int* dst = ei + E;
    const int GP = (E + ECHUNK - 1) / ECHUNK;  // 391

    char* ws = (char*)d_ws;
    size_t off = 0;
    auto alloc = [&](size_t bytes) {
        char* p = ws + off;
        off += (bytes + 511) & ~size_t(511);
        return p;
    };
    int*    fills  = (int*)alloc((NC + KF) * sizeof(int));
    float*  dinv   = (float*)alloc(N * sizeof(float));
    float2* sx     = (float2*)alloc(N * sizeof(float2));
    float2* sz     = (float2*)alloc(N * sizeof(float2));
    int*    slotsC = (int*)alloc((size_t)NC * CAP1 * sizeof(int));  // 13.4 MB
    int*    slotsF = (int*)alloc((size_t)KF * CAPF * sizeof(int));  // 16.1 MB
    int* gfill1 = fills;
    int* gfillF = fills + NC;

    hipMemsetAsync(fills, 0, (NC + KF) * sizeof(int), stream);

    k_pass1<<<GP, BSP, 0, stream>>>(src, dst, E, gfill1, slotsC);
    k_pass2<<<NC * MAXCH, BSP, 0, stream>>>(gfill1, slotsC, gfillF, slotsF);
    k_deg<<<K, 256, 0, stream>>>(gfillF, slotsF, x, dinv, sx);
    k_agg1<<<K, 256, 0, stream>>>(gfillF, slotsF, dinv, sx, W1, b1, W2, sz);
    k_agg2<<<K, 256, 0, stream>>>(gfillF, slotsF, dinv, sz, b2, (float2*)d_out);
}